// Round 2
// baseline (1654.264 us; speedup 1.0000x reference)
//
#include <hip/hip_runtime.h>

using v8bf  = __bf16 __attribute__((ext_vector_type(8)));
using v16f  = float  __attribute__((ext_vector_type(16)));

#define EPS_BN 1e-5f
#define ATT_SCALE 0.044194173824159216f   // 512^-0.5

__device__ __forceinline__ unsigned short f2bf(float f){
  union { float f; unsigned int u; } c; c.f = f;
  unsigned int u = c.u + 0x7fffu + ((c.u >> 16) & 1u);
  return (unsigned short)(u >> 16);
}

__device__ __forceinline__ v8bf ld_v8bf_g(const unsigned short* p){
  union { uint4 u; v8bf v; } c;
  c.u = *(const uint4*)p;
  return c.v;
}

// ---------------- cast fp32 -> bf16 (8 elems/thread) ----------------
__global__ void cast_bf16_kernel(const float* __restrict__ src,
                                 unsigned short* __restrict__ dst, int n8){
  int i = blockIdx.x * 256 + threadIdx.x;
  if (i >= n8) return;
  const float4* s4 = (const float4*)src;
  float4 a = s4[2*i], b = s4[2*i+1];
  union { unsigned short s[8]; uint4 u; } r;
  r.s[0]=f2bf(a.x); r.s[1]=f2bf(a.y); r.s[2]=f2bf(a.z); r.s[3]=f2bf(a.w);
  r.s[4]=f2bf(b.x); r.s[5]=f2bf(b.y); r.s[6]=f2bf(b.z); r.s[7]=f2bf(b.w);
  ((uint4*)dst)[i] = r.u;
}

// ---------------- BN affine precompute ----------------
__global__ void bn_precompute(const float* __restrict__ g, const float* __restrict__ be,
                              const float* __restrict__ mn, const float* __restrict__ vr,
                              float* __restrict__ scale, float* __restrict__ shift,
                              int n, int qfold){
  int i = blockIdx.x * 256 + threadIdx.x;
  if (i >= n) return;
  float s = g[i] * rsqrtf(vr[i] + EPS_BN);
  float t = be[i] - mn[i] * s;
  if (qfold && (i & 1023) < 256){ s *= ATT_SCALE; t *= ATT_SCALE; }
  scale[i] = s; shift[i] = t;
}

// ---------------- generic NT GEMM, 128x128 tile, BK=32 ----------------
// MODE 0: qkv projection, BN epilogue, scatter Q/K/V (bf16), group-local
// MODE 1: PV, clamp [-1,1] epilogue -> outc bf16 [G*1024, 4096], group-local
// MODE 2: proj, BN epilogue -> fp32 out rows offset by mbase
template<int MODE>
__launch_bounds__(256, 2)
__global__ void gemm_nt(const unsigned short* __restrict__ A,
                        const unsigned short* __restrict__ Bm,
                        int K, long sA, long sB, long mbase,
                        const float* __restrict__ scale, const float* __restrict__ shift,
                        unsigned short* __restrict__ qo, unsigned short* __restrict__ ko_,
                        unsigned short* __restrict__ vo,
                        unsigned short* __restrict__ outc,
                        float* __restrict__ outf)
{
  __shared__ __align__(16) unsigned short As[128*40];
  __shared__ __align__(16) unsigned short Bs[128*40];
  const int tid = threadIdx.x;
  const int w = tid >> 6, lane = tid & 63, ln = lane & 31, lg = lane >> 5;
  const int wm = (w >> 1) * 64, wn = (w & 1) * 64;
  const long bm = (long)blockIdx.y * 128, bn = (long)blockIdx.x * 128;
  const int z = blockIdx.z;
  const unsigned short* Ab = A + (long)z * sA + bm * K;
  const unsigned short* Bb = Bm + (long)z * sB + bn * K;

  v16f acc[2][2];
  #pragma unroll
  for (int a = 0; a < 2; a++)
    #pragma unroll
    for (int b = 0; b < 2; b++)
      #pragma unroll
      for (int i = 0; i < 16; i++) acc[a][b][i] = 0.f;

  for (int k0 = 0; k0 < K; k0 += 32){
    __syncthreads();
    #pragma unroll
    for (int s = 0; s < 2; s++){
      int seg = tid + s * 256;           // 512 segs of 8 bf16
      int row = seg >> 2, koff = (seg & 3) * 8;
      *(uint4*)&As[row*40 + koff] = *(const uint4*)(Ab + (long)row*K + k0 + koff);
      *(uint4*)&Bs[row*40 + koff] = *(const uint4*)(Bb + (long)row*K + k0 + koff);
    }
    __syncthreads();
    #pragma unroll
    for (int kk = 0; kk < 32; kk += 16){
      v8bf af[2], bfr[2];
      #pragma unroll
      for (int t = 0; t < 2; t++){
        af[t]  = *(const v8bf*)&As[(wm + t*32 + ln)*40 + kk + lg*8];
        bfr[t] = *(const v8bf*)&Bs[(wn + t*32 + ln)*40 + kk + lg*8];
      }
      #pragma unroll
      for (int tm = 0; tm < 2; tm++)
        #pragma unroll
        for (int tn = 0; tn < 2; tn++)
          acc[tm][tn] = __builtin_amdgcn_mfma_f32_32x32x16_bf16(af[tm], bfr[tn], acc[tm][tn], 0, 0, 0);
    }
  }

  #pragma unroll
  for (int tm = 0; tm < 2; tm++){
    #pragma unroll
    for (int tn = 0; tn < 2; tn++){
      long gn = bn + wn + tn*32 + ln;
      float sc = 0.f, sh = 0.f;
      if (MODE == 0 || MODE == 2){ sc = scale[gn]; sh = shift[gn]; }
      #pragma unroll
      for (int i = 0; i < 16; i++){
        long gm = bm + wm + tm*32 + (i&3) + 8*(i>>2) + 4*lg;
        float v = acc[tm][tn][i];
        if (MODE == 0){
          v = v * sc + sh;
          unsigned short bv = f2bf(v);
          int bb = (int)(gm >> 10), n = (int)(gm & 1023);
          int h  = (int)(gn >> 10), r = (int)(gn & 1023);
          long base = ((long)(bb*8 + h) * 1024 + n);
          if (r < 256)      qo [base*256 + r] = bv;
          else if (r < 512) ko_[base*256 + (r - 256)] = bv;
          else              vo [base*512 + (r - 512)] = bv;
        } else if (MODE == 1){
          v = fminf(1.f, fmaxf(-1.f, v));
          int b2 = z >> 3, h = z & 7;
          outc[((long)b2*1024 + gm)*4096 + h*512 + gn] = f2bf(v);
        } else {
          outf[(mbase + gm)*512 + gn] = v * sc + sh;
        }
      }
    }
  }
}

// ---------------- V [bh,1024,512] -> Vt [bh,512,1024] (group-local) ------
__global__ void transpose_v(const unsigned short* __restrict__ V,
                            unsigned short* __restrict__ Vt){
  __shared__ __align__(16) unsigned short Ts[64*72];
  int bh = blockIdx.z;
  int n0 = blockIdx.x * 64, d0 = blockIdx.y * 64;
  int tid = threadIdx.x;
  const unsigned short* Vb = V + (long)bh * 524288;
  unsigned short* Vtb = Vt + (long)bh * 524288;
  #pragma unroll
  for (int i = 0; i < 2; i++){
    int seg = tid + i*256;
    int row = seg >> 3, co = (seg & 7) * 8;
    *(uint4*)&Ts[row*72 + co] = *(const uint4*)(Vb + (long)(n0 + row)*512 + d0 + co);
  }
  __syncthreads();
  #pragma unroll
  for (int i = 0; i < 2; i++){
    int seg = tid + i*256;
    int drow = seg >> 3, nco = (seg & 7) * 8;
    union { unsigned short s[8]; uint4 u; } r;
    #pragma unroll
    for (int j = 0; j < 8; j++) r.s[j] = Ts[(nco + j)*72 + drow];
    *(uint4*)(Vtb + (long)(d0 + drow)*1024 + n0 + nco) = r.u;
  }
}

// ---------------- fused scores + softmax -> P bf16 (group-local) ---------
// block: 256 thr (4 waves). 32 query rows per block; wave w owns keys [w*256, w*256+256).
// K fragments load DIRECTLY from global (B-frag pattern = vectorized row read).
__launch_bounds__(256, 1)
__global__ void attn_softmax(const unsigned short* __restrict__ Q,
                             const unsigned short* __restrict__ Kt,
                             const float* __restrict__ bias,
                             unsigned short* __restrict__ P)
{
  __shared__ float red[2][4][32];
  int bh = blockIdx.y, mblk = blockIdx.x;
  int h = bh & 7;
  int tid = threadIdx.x, w = tid >> 6, lane = tid & 63, ln = lane & 31, lg = lane >> 5;
  int m0 = mblk * 32;
  const unsigned short* Qb = Q + (long)bh * 262144;
  const unsigned short* Kb = Kt + (long)bh * 262144;
  const float* biash = bias + (long)h * 1048576;
  unsigned short* Pb = P + (long)bh * 1048576;

  // Q fragments in registers: A[m=ln][k = kf*16 + lg*8 + j]
  v8bf qf[16];
  {
    const unsigned short* qrow = Qb + (long)(m0 + ln)*256 + lg*8;
    #pragma unroll
    for (int kf = 0; kf < 16; kf++) qf[kf] = ld_v8bf_g(qrow + kf*16);
  }

  float S[8][16];
  for (int t = 0; t < 8; t++){
    const unsigned short* krow = Kb + (long)(w*256 + t*32 + ln)*256 + lg*8;
    v16f acc0, acc1;
    #pragma unroll
    for (int i = 0; i < 16; i++){ acc0[i] = 0.f; acc1[i] = 0.f; }
    #pragma unroll
    for (int kf = 0; kf < 16; kf += 2){
      v8bf k0 = ld_v8bf_g(krow + kf*16);
      v8bf k1 = ld_v8bf_g(krow + kf*16 + 16);
      acc0 = __builtin_amdgcn_mfma_f32_32x32x16_bf16(qf[kf],   k0, acc0, 0, 0, 0);
      acc1 = __builtin_amdgcn_mfma_f32_32x32x16_bf16(qf[kf+1], k1, acc1, 0, 0, 0);
    }
    int col = w*256 + t*32 + ln;
    #pragma unroll
    for (int i = 0; i < 16; i++){
      int r = (i&3) + 8*(i>>2) + 4*lg;
      S[t][i] = acc0[i] + acc1[i] + biash[(long)(m0 + r)*1024 + col];
    }
  }

  // row max: 8 tiles -> 32 key-lanes -> 4 waves
  float mx[16];
  #pragma unroll
  for (int i = 0; i < 16; i++){
    float m = S[0][i];
    #pragma unroll
    for (int t = 1; t < 8; t++) m = fmaxf(m, S[t][i]);
    #pragma unroll
    for (int d = 1; d < 32; d <<= 1) m = fmaxf(m, __shfl_xor(m, d, 64));
    mx[i] = m;
  }
  if (ln == 0){
    #pragma unroll
    for (int i = 0; i < 16; i++){
      int r = (i&3) + 8*(i>>2) + 4*lg;
      red[0][w][r] = mx[i];
    }
  }
  __syncthreads();
  #pragma unroll
  for (int i = 0; i < 16; i++){
    int r = (i&3) + 8*(i>>2) + 4*lg;
    mx[i] = fmaxf(fmaxf(red[0][0][r], red[0][1][r]), fmaxf(red[0][2][r], red[0][3][r]));
  }

  // exp + row sum
  float sm[16];
  #pragma unroll
  for (int i = 0; i < 16; i++){
    float s = 0.f;
    #pragma unroll
    for (int t = 0; t < 8; t++){
      float e = __expf(S[t][i] - mx[i]);
      S[t][i] = e;
      s += e;
    }
    #pragma unroll
    for (int d = 1; d < 32; d <<= 1) s += __shfl_xor(s, d, 64);
    sm[i] = s;
  }
  if (ln == 0){
    #pragma unroll
    for (int i = 0; i < 16; i++){
      int r = (i&3) + 8*(i>>2) + 4*lg;
      red[1][w][r] = sm[i];
    }
  }
  __syncthreads();
  #pragma unroll
  for (int i = 0; i < 16; i++){
    int r = (i&3) + 8*(i>>2) + 4*lg;
    float inv = 1.f / (red[1][0][r] + red[1][1][r] + red[1][2][r] + red[1][3][r]);
    #pragma unroll
    for (int t = 0; t < 8; t++){
      int col = w*256 + t*32 + ln;
      Pb[(long)(m0 + r)*1024 + col] = f2bf(S[t][i] * inv);
    }
  }
}

extern "C" void kernel_launch(void* const* d_in, const int* in_sizes, int n_in,
                              void* d_out, int out_size, void* d_ws, size_t ws_size,
                              hipStream_t stream)
{
  const float* x        = (const float*)d_in[0];
  const float* qkv_w    = (const float*)d_in[1];
  const float* qg       = (const float*)d_in[2];
  const float* qb       = (const float*)d_in[3];
  const float* qm       = (const float*)d_in[4];
  const float* qv       = (const float*)d_in[5];
  const float* pos_bias = (const float*)d_in[6];
  const float* pw       = (const float*)d_in[7];
  const float* pg       = (const float*)d_in[8];
  const float* pbt      = (const float*)d_in[9];
  const float* pmn      = (const float*)d_in[10];
  const float* pvr      = (const float*)d_in[11];
  float* out = (float*)d_out;

  // ---- adaptive workspace layout: fixed 16.85MB + G*51.9MB ----
  const unsigned long FIXED = 16846848UL;
  const unsigned long PERG  = 51904512UL;
  long G = 1;
  if      (ws_size >= FIXED + PERG*16) G = 16;
  else if (ws_size >= FIXED + PERG*8)  G = 8;
  else if (ws_size >= FIXED + PERG*4)  G = 4;
  else if (ws_size >= FIXED + PERG*2)  G = 2;
  else if (ws_size >= FIXED + PERG)    G = 1;
  else return;  // cannot run at all (ws < 69MB)

  char* ws = (char*)d_ws;
  unsigned short* wqb = (unsigned short*)(ws + 0L);            // 12,582,912
  unsigned short* wpb = (unsigned short*)(ws + 12582912L);     //  4,194,304
  float* sc_qkv       = (float*)(ws + 16777216L);              //     32,768
  float* sh_qkv       = (float*)(ws + 16809984L);              //     32,768
  float* sc_p         = (float*)(ws + 16842752L);              //      2,048
  float* sh_p         = (float*)(ws + 16844800L);              //      2,048
  long gb = 16846848L;
  unsigned short* xbg   = (unsigned short*)(ws + gb);                      // G*1,572,864
  unsigned short* Qg    = (unsigned short*)(ws + gb + G*1572864L);         // G*4,194,304
  unsigned short* Kg    = (unsigned short*)(ws + gb + G*5767168L);         // G*4,194,304
  unsigned short* Vg    = (unsigned short*)(ws + gb + G*9961472L);         // G*8,388,608
  unsigned short* Vtg   = (unsigned short*)(ws + gb + G*18350080L);        // G*8,388,608
  unsigned short* Pg    = (unsigned short*)(ws + gb + G*26738688L);        // G*16,777,216
  unsigned short* outcg = (unsigned short*)(ws + gb + G*43515904L);        // G*8,388,608

  // weights + BN affines (once)
  cast_bf16_kernel<<<dim3(3072), 256, 0, stream>>>(qkv_w, wqb, 786432);
  cast_bf16_kernel<<<dim3(1024), 256, 0, stream>>>(pw,    wpb, 262144);
  bn_precompute<<<dim3(32), 256, 0, stream>>>(qg, qb, qm, qv, sc_qkv, sh_qkv, 8192, 1);
  bn_precompute<<<dim3(2),  256, 0, stream>>>(pg, pbt, pmn, pvr, sc_p, sh_p, 512, 0);

  const int nG = (int)(16 / G);
  for (int g = 0; g < nG; g++){
    const float* xg = x + (long)g * G * 786432L;
    long mbase = (long)g * G * 1024L;

    // x chunk -> bf16
    cast_bf16_kernel<<<dim3((unsigned)(G*384)), 256, 0, stream>>>(xg, xbg, (int)(G*98304));

    // qkv = BN(x @ qkv_w^T) -> Q,K,V (group-local)
    gemm_nt<0><<<dim3(64, (unsigned)(8*G), 1), 256, 0, stream>>>(
        xbg, wqb, 768, 0L, 0L, 0L, sc_qkv, sh_qkv, Qg, Kg, Vg, nullptr, nullptr);

    // V -> V^T
    transpose_v<<<dim3(16, 8, (unsigned)(8*G)), 256, 0, stream>>>(Vg, Vtg);

    // P = softmax(Q K^T + bias)
    attn_softmax<<<dim3(32, (unsigned)(8*G)), 256, 0, stream>>>(Qg, Kg, pos_bias, Pg);

    // outc = clamp(P @ V, -1, 1)
    gemm_nt<1><<<dim3(4, 8, (unsigned)(8*G)), 256, 0, stream>>>(
        Pg, Vtg, 1024, 1048576L, 524288L, 0L, nullptr, nullptr,
        nullptr, nullptr, nullptr, outcg, nullptr);

    // out rows [mbase, mbase+G*1024) = BN(outc @ proj_w^T)
    gemm_nt<2><<<dim3(4, (unsigned)(8*G), 1), 256, 0, stream>>>(
        outcg, wpb, 4096, 0L, 0L, mbase, sc_p, sh_p,
        nullptr, nullptr, nullptr, nullptr, out);
  }
}

// Round 3
// 1609.379 us; speedup vs baseline: 1.0279x; 1.0279x over previous
//
#include <hip/hip_runtime.h>

using v8bf  = __bf16 __attribute__((ext_vector_type(8)));
using v16f  = float  __attribute__((ext_vector_type(16)));

#define EPS_BN 1e-5f
#define ATT_SCALE 0.044194173824159216f   // 512^-0.5

__device__ __forceinline__ unsigned short f2bf(float f){
  union { float f; unsigned int u; } c; c.f = f;
  unsigned int u = c.u + 0x7fffu + ((c.u >> 16) & 1u);
  return (unsigned short)(u >> 16);
}

__device__ __forceinline__ v8bf ld8(const unsigned short* p){
  union { uint4 u; v8bf v; } c;
  c.u = *(const uint4*)p;
  return c.v;
}

// async global->LDS, 16B per lane; LDS dest = uniform base + lane*16
__device__ __forceinline__ void glds16(const unsigned short* g, unsigned short* l){
  __builtin_amdgcn_global_load_lds(
      (const __attribute__((address_space(1))) void*)g,
      (__attribute__((address_space(3))) void*)l, 16, 0, 0);
}

// ---------------- cast fp32 -> bf16 (8 elems/thread) ----------------
__global__ void cast_bf16_kernel(const float* __restrict__ src,
                                 unsigned short* __restrict__ dst, int n8){
  int i = blockIdx.x * 256 + threadIdx.x;
  if (i >= n8) return;
  const float4* s4 = (const float4*)src;
  float4 a = s4[2*i], b = s4[2*i+1];
  union { unsigned short s[8]; uint4 u; } r;
  r.s[0]=f2bf(a.x); r.s[1]=f2bf(a.y); r.s[2]=f2bf(a.z); r.s[3]=f2bf(a.w);
  r.s[4]=f2bf(b.x); r.s[5]=f2bf(b.y); r.s[6]=f2bf(b.z); r.s[7]=f2bf(b.w);
  ((uint4*)dst)[i] = r.u;
}

// ---------------- BN affine precompute ----------------
__global__ void bn_precompute(const float* __restrict__ g, const float* __restrict__ be,
                              const float* __restrict__ mn, const float* __restrict__ vr,
                              float* __restrict__ scale, float* __restrict__ shift,
                              int n, int qfold){
  int i = blockIdx.x * 256 + threadIdx.x;
  if (i >= n) return;
  float s = g[i] * rsqrtf(vr[i] + EPS_BN);
  float t = be[i] - mn[i] * s;
  if (qfold && (i & 1023) < 256){ s *= ATT_SCALE; t *= ATT_SCALE; }
  scale[i] = s; shift[i] = t;
}

// ---------------- bias [h][row][col] -> biasT [h][col][row] ----------------
__global__ void transpose_bias(const float* __restrict__ Bsrc, float* __restrict__ BT){
  __shared__ float Ts[64][65];
  const int h = blockIdx.z;
  const int r0 = blockIdx.x * 64, c0 = blockIdx.y * 64;
  const int tid = threadIdx.x;
  const float* Bb = Bsrc + (long)h * 1048576;
  float* Tb = BT + (long)h * 1048576;
  #pragma unroll
  for (int it = 0; it < 4; it++){
    int idx = tid + it * 256;
    int row = idx >> 4, c4 = (idx & 15) * 4;
    float4 v = *(const float4*)(Bb + (long)(r0 + row) * 1024 + c0 + c4);
    Ts[row][c4] = v.x; Ts[row][c4+1] = v.y; Ts[row][c4+2] = v.z; Ts[row][c4+3] = v.w;
  }
  __syncthreads();
  #pragma unroll
  for (int it = 0; it < 4; it++){
    int idx = tid + it * 256;
    int cc = idx >> 4, r4 = (idx & 15) * 4;
    float4 v = { Ts[r4][cc], Ts[r4+1][cc], Ts[r4+2][cc], Ts[r4+3][cc] };
    *(float4*)(Tb + (long)(c0 + cc) * 1024 + r0 + r4) = v;
  }
}

// ---------------- generic NT GEMM, 128x128 tile, BK=32, global_load_lds ----
// LDS layout: unpadded [row][granule(8 halves)] with XOR swizzle slot = g ^ ((row>>1)&3)
// MODE 0: qkv projection, BN epilogue, scatter Q/K (row-major) + V^T (bf16)
// MODE 1: PV, *invsum + clamp epilogue -> outc bf16 [G*1024, 4096]
// MODE 2: proj, BN epilogue -> fp32 out rows offset by mbase
template<int MODE>
__launch_bounds__(256, 2)
__global__ void gemm_nt(const unsigned short* __restrict__ A,
                        const unsigned short* __restrict__ Bm,
                        int K, long sA, long sB, long mbase,
                        const float* __restrict__ scale, const float* __restrict__ shift,
                        const float* __restrict__ sums,
                        unsigned short* __restrict__ qo, unsigned short* __restrict__ ko_,
                        unsigned short* __restrict__ vo,
                        unsigned short* __restrict__ outc,
                        float* __restrict__ outf)
{
  __shared__ __align__(16) unsigned short As[4096];
  __shared__ __align__(16) unsigned short Bs[4096];
  const int tid = threadIdx.x;
  const int w = tid >> 6, lane = tid & 63, ln = lane & 31, lg = lane >> 5;
  const int wm = (w >> 1) * 64, wn = (w & 1) * 64;
  const long bm = (long)blockIdx.y * 128, bn = (long)blockIdx.x * 128;
  const int z = blockIdx.z;
  const unsigned short* Ab = A + (long)z * sA + bm * K;
  const unsigned short* Bb = Bm + (long)z * sB + bn * K;

  // staging: wave w covers tile rows [w*32, w*32+32) in two 16-row instrs
  const int srow0 = w*32 + (lane >> 2);
  const int srow1 = srow0 + 16;
  const int slot  = lane & 3;
  const int ga0 = (slot ^ ((srow0 >> 1) & 3)) * 8;   // global granule (halves)
  const int ga1 = (slot ^ ((srow1 >> 1) & 3)) * 8;
  const unsigned short* gA0 = Ab + (long)srow0 * K + ga0;
  const unsigned short* gA1 = Ab + (long)srow1 * K + ga1;
  const unsigned short* gB0 = Bb + (long)srow0 * K + ga0;
  const unsigned short* gB1 = Bb + (long)srow1 * K + ga1;
  unsigned short* lA0 = As + (w*32)*32;
  unsigned short* lA1 = As + (w*32+16)*32;
  unsigned short* lB0 = Bs + (w*32)*32;
  unsigned short* lB1 = Bs + (w*32+16)*32;

  v16f acc[2][2];
  #pragma unroll
  for (int a = 0; a < 2; a++)
    #pragma unroll
    for (int b = 0; b < 2; b++)
      #pragma unroll
      for (int i = 0; i < 16; i++) acc[a][b][i] = 0.f;

  for (int k0 = 0; k0 < K; k0 += 32){
    __syncthreads();
    glds16(gA0 + k0, lA0);
    glds16(gA1 + k0, lA1);
    glds16(gB0 + k0, lB0);
    glds16(gB1 + k0, lB1);
    __syncthreads();
    #pragma unroll
    for (int kk = 0; kk < 32; kk += 16){
      v8bf af[2], bfr[2];
      #pragma unroll
      for (int t = 0; t < 2; t++){
        int Ra = wm + t*32 + ln;
        int sa = ((kk>>3) + lg) ^ ((Ra >> 1) & 3);
        af[t] = *(const v8bf*)&As[Ra*32 + sa*8];
        int Rb = wn + t*32 + ln;
        int sb = ((kk>>3) + lg) ^ ((Rb >> 1) & 3);
        bfr[t] = *(const v8bf*)&Bs[Rb*32 + sb*8];
      }
      #pragma unroll
      for (int tm = 0; tm < 2; tm++)
        #pragma unroll
        for (int tn = 0; tn < 2; tn++)
          acc[tm][tn] = __builtin_amdgcn_mfma_f32_32x32x16_bf16(af[tm], bfr[tn], acc[tm][tn], 0, 0, 0);
    }
  }

  float invs[2][16];
  if (MODE == 1){
    #pragma unroll
    for (int tm = 0; tm < 2; tm++)
      #pragma unroll
      for (int i = 0; i < 16; i++){
        long gm = bm + wm + tm*32 + (i&3) + 8*(i>>2) + 4*lg;
        invs[tm][i] = 1.0f / sums[(long)z*1024 + gm];
      }
  }

  #pragma unroll
  for (int tm = 0; tm < 2; tm++){
    #pragma unroll
    for (int tn = 0; tn < 2; tn++){
      long gn = bn + wn + tn*32 + ln;
      float sc = 0.f, sh = 0.f;
      if (MODE == 0 || MODE == 2){ sc = scale[gn]; sh = shift[gn]; }
      #pragma unroll
      for (int i = 0; i < 16; i++){
        long gm = bm + wm + tm*32 + (i&3) + 8*(i>>2) + 4*lg;
        float v = acc[tm][tn][i];
        if (MODE == 0){
          v = v * sc + sh;
          unsigned short bv = f2bf(v);
          int bb = (int)(gm >> 10), n = (int)(gm & 1023);
          int hh = (int)(gn >> 10), r = (int)(gn & 1023);
          if (r < 256)      qo [((long)(bb*8 + hh)*1024 + n)*256 + r] = bv;
          else if (r < 512) ko_[((long)(bb*8 + hh)*1024 + n)*256 + (r - 256)] = bv;
          else              vo [((long)(bb*8 + hh)*512 + (r - 512))*1024 + n] = bv;   // V^T
        } else if (MODE == 1){
          v = v * invs[tm][i];
          v = fminf(1.f, fmaxf(-1.f, v));
          int b2 = z >> 3, hh = z & 7;
          outc[((long)b2*1024 + gm)*4096 + hh*512 + gn] = f2bf(v);
        } else {
          outf[(mbase + gm)*512 + gn] = v * sc + sh;
        }
      }
    }
  }
}

// ---------------- attention scores: E = exp(QK^T*scale + bias), row sums ----
// grid (8 m-blocks, bh). 4 waves; wave w owns 32 query rows, sweeps all 1024 keys.
// No max subtraction (scores BN-bounded << 88). E unnormalized bf16; 1/sum folded into PV.
__launch_bounds__(256, 2)
__global__ void attn_scores(const unsigned short* __restrict__ Q,
                            const unsigned short* __restrict__ Kt,
                            const float* __restrict__ biasT,   // [h][col][row]
                            unsigned short* __restrict__ E,
                            float* __restrict__ sums)
{
  const int bh = blockIdx.y, mblk = blockIdx.x;
  const int h = bh & 7;
  const int tid = threadIdx.x, w = tid >> 6, lane = tid & 63, ln = lane & 31, lg = lane >> 5;
  const int m0 = mblk * 128 + w * 32;
  const unsigned short* Qb = Q + (long)bh * 262144;
  const unsigned short* Kb = Kt + (long)bh * 262144;
  const float* bT = biasT + (long)h * 1048576;
  unsigned short* Eb = E + (long)bh * 1048576;

  v8bf qf[16];
  {
    const unsigned short* qrow = Qb + (long)(m0 + ln) * 256 + lg * 8;
    #pragma unroll
    for (int kf = 0; kf < 16; kf++) qf[kf] = ld8(qrow + kf * 16);
  }

  float sm[16];
  #pragma unroll
  for (int i = 0; i < 16; i++) sm[i] = 0.f;

  for (int t = 0; t < 32; t++){
    const unsigned short* krow = Kb + (long)(t*32 + ln) * 256 + lg * 8;
    v16f a0, a1;
    #pragma unroll
    for (int i = 0; i < 16; i++){ a0[i] = 0.f; a1[i] = 0.f; }
    #pragma unroll
    for (int kf = 0; kf < 16; kf += 2){
      v8bf k0 = ld8(krow + kf*16);
      v8bf k1 = ld8(krow + kf*16 + 16);
      a0 = __builtin_amdgcn_mfma_f32_32x32x16_bf16(qf[kf],   k0, a0, 0, 0, 0);
      a1 = __builtin_amdgcn_mfma_f32_32x32x16_bf16(qf[kf+1], k1, a1, 0, 0, 0);
    }
    const int col = t*32 + ln;
    const float* bp = bT + (long)col * 1024 + m0 + 4*lg;
    unsigned short* ep = Eb + col;
    #pragma unroll
    for (int q = 0; q < 4; q++){
      float4 b4 = *(const float4*)(bp + 8*q);
      #pragma unroll
      for (int j = 0; j < 4; j++){
        int i = q*4 + j;
        float e = __expf(a0[i] + a1[i] + (&b4.x)[j]);
        sm[i] += e;
        ep[(long)(m0 + 4*lg + 8*q + j) * 1024] = f2bf(e);
      }
    }
  }

  #pragma unroll
  for (int i = 0; i < 16; i++){
    #pragma unroll
    for (int d = 1; d < 32; d <<= 1) sm[i] += __shfl_xor(sm[i], d, 64);
  }
  if (ln == 0){
    float* sp = sums + (long)bh * 1024 + m0 + 4*lg;
    #pragma unroll
    for (int q = 0; q < 4; q++)
      #pragma unroll
      for (int j = 0; j < 4; j++)
        sp[8*q + j] = sm[q*4 + j];
  }
}

extern "C" void kernel_launch(void* const* d_in, const int* in_sizes, int n_in,
                              void* d_out, int out_size, void* d_ws, size_t ws_size,
                              hipStream_t stream)
{
  const float* x        = (const float*)d_in[0];
  const float* qkv_w    = (const float*)d_in[1];
  const float* qg       = (const float*)d_in[2];
  const float* qb       = (const float*)d_in[3];
  const float* qm       = (const float*)d_in[4];
  const float* qv       = (const float*)d_in[5];
  const float* pos_bias = (const float*)d_in[6];
  const float* pw       = (const float*)d_in[7];
  const float* pg       = (const float*)d_in[8];
  const float* pbt      = (const float*)d_in[9];
  const float* pmn      = (const float*)d_in[10];
  const float* pvr      = (const float*)d_in[11];
  float* out = (float*)d_out;

  // ---- adaptive workspace: FIXED 50.4MB + G*43.5MB ----
  const unsigned long FIXED = 50401280UL;
  const unsigned long PERG  = 43548672UL;
  long G = 1;
  if      (ws_size >= FIXED + PERG*16) G = 16;
  else if (ws_size >= FIXED + PERG*8)  G = 8;
  else if (ws_size >= FIXED + PERG*4)  G = 4;
  else if (ws_size >= FIXED + PERG*2)  G = 2;
  else if (ws_size >= FIXED + PERG)    G = 1;
  else return;

  char* ws = (char*)d_ws;
  unsigned short* wqb = (unsigned short*)(ws + 0L);            // 12,582,912
  unsigned short* wpb = (unsigned short*)(ws + 12582912L);     //  4,194,304
  float* sc_qkv       = (float*)(ws + 16777216L);              //     32,768
  float* sh_qkv       = (float*)(ws + 16809984L);              //     32,768
  float* sc_p         = (float*)(ws + 16842752L);              //      2,048
  float* sh_p         = (float*)(ws + 16844800L);              //      2,048
  float* biasT        = (float*)(ws + 16846848L);              // 33,554,432
  long gb = 50401280L;
  unsigned short* xbg   = (unsigned short*)(ws + gb);                      // G*1,572,864
  unsigned short* Qg    = (unsigned short*)(ws + gb + G*1572864L);         // G*4,194,304
  unsigned short* Kg    = (unsigned short*)(ws + gb + G*5767168L);         // G*4,194,304
  unsigned short* Vtg   = (unsigned short*)(ws + gb + G*9961472L);         // G*8,388,608
  unsigned short* Eg    = (unsigned short*)(ws + gb + G*18350080L);        // G*16,777,216
  unsigned short* outcg = (unsigned short*)(ws + gb + G*35127296L);        // G*8,388,608
  float* sumsg          = (float*)(ws + gb + G*43515904L);                 // G*32,768

  // weights + BN affines + bias transpose (once)
  cast_bf16_kernel<<<dim3(3072), 256, 0, stream>>>(qkv_w, wqb, 786432);
  cast_bf16_kernel<<<dim3(1024), 256, 0, stream>>>(pw,    wpb, 262144);
  bn_precompute<<<dim3(32), 256, 0, stream>>>(qg, qb, qm, qv, sc_qkv, sh_qkv, 8192, 1);
  bn_precompute<<<dim3(2),  256, 0, stream>>>(pg, pbt, pmn, pvr, sc_p, sh_p, 512, 0);
  transpose_bias<<<dim3(16, 16, 8), 256, 0, stream>>>(pos_bias, biasT);

  const int nG = (int)(16 / G);
  for (int g = 0; g < nG; g++){
    const float* xg = x + (long)g * G * 786432L;
    long mbase = (long)g * G * 1024L;

    cast_bf16_kernel<<<dim3((unsigned)(G*384)), 256, 0, stream>>>(xg, xbg, (int)(G*98304));

    // qkv = BN(x @ qkv_w^T) -> Q,K row-major + V^T
    gemm_nt<0><<<dim3(64, (unsigned)(8*G), 1), 256, 0, stream>>>(
        xbg, wqb, 768, 0L, 0L, 0L, sc_qkv, sh_qkv, nullptr,
        Qg, Kg, Vtg, nullptr, nullptr);

    // E = exp(QK^T + bias), rowsums
    attn_scores<<<dim3(8, (unsigned)(8*G)), 256, 0, stream>>>(Qg, Kg, biasT, Eg, sumsg);

    // outc = clamp((E @ V) / sum, -1, 1)
    gemm_nt<1><<<dim3(4, 8, (unsigned)(8*G)), 256, 0, stream>>>(
        Eg, Vtg, 1024, 1048576L, 524288L, 0L, nullptr, nullptr, sumsg,
        nullptr, nullptr, nullptr, outcg, nullptr);

    // out rows [mbase, mbase+G*1024) = BN(outc @ proj_w^T)
    gemm_nt<2><<<dim3(4, (unsigned)(8*G), 1), 256, 0, stream>>>(
        outcg, wpb, 4096, 0L, 0L, mbase, sc_p, sh_p, nullptr,
        nullptr, nullptr, nullptr, nullptr, out);
  }
}

// Round 4
// 1312.291 us; speedup vs baseline: 1.2606x; 1.2264x over previous
//
#include <hip/hip_runtime.h>

using v8bf  = __bf16 __attribute__((ext_vector_type(8)));
using v16f  = float  __attribute__((ext_vector_type(16)));

#define EPS_BN 1e-5f
#define ATT_SCALE 0.044194173824159216f   // 512^-0.5

__device__ __forceinline__ unsigned short f2bf(float f){
  union { float f; unsigned int u; } c; c.f = f;
  unsigned int u = c.u + 0x7fffu + ((c.u >> 16) & 1u);
  return (unsigned short)(u >> 16);
}

__device__ __forceinline__ v8bf ld8(const unsigned short* p){
  union { uint4 u; v8bf v; } c;
  c.u = *(const uint4*)p;
  return c.v;
}

// async global->LDS, 16B per lane; LDS dest = uniform base + lane*16
__device__ __forceinline__ void glds16(const unsigned short* g, unsigned short* l){
  __builtin_amdgcn_global_load_lds(
      (const __attribute__((address_space(1))) void*)g,
      (__attribute__((address_space(3))) void*)l, 16, 0, 0);
}

// ---------------- cast fp32 -> bf16 (8 elems/thread) ----------------
__global__ void cast_bf16_kernel(const float* __restrict__ src,
                                 unsigned short* __restrict__ dst, int n8){
  int i = blockIdx.x * 256 + threadIdx.x;
  if (i >= n8) return;
  const float4* s4 = (const float4*)src;
  float4 a = s4[2*i], b = s4[2*i+1];
  union { unsigned short s[8]; uint4 u; } r;
  r.s[0]=f2bf(a.x); r.s[1]=f2bf(a.y); r.s[2]=f2bf(a.z); r.s[3]=f2bf(a.w);
  r.s[4]=f2bf(b.x); r.s[5]=f2bf(b.y); r.s[6]=f2bf(b.z); r.s[7]=f2bf(b.w);
  ((uint4*)dst)[i] = r.u;
}

// ---------------- BN affine precompute ----------------
__global__ void bn_precompute(const float* __restrict__ g, const float* __restrict__ be,
                              const float* __restrict__ mn, const float* __restrict__ vr,
                              float* __restrict__ scale, float* __restrict__ shift,
                              int n, int qfold){
  int i = blockIdx.x * 256 + threadIdx.x;
  if (i >= n) return;
  float s = g[i] * rsqrtf(vr[i] + EPS_BN);
  float t = be[i] - mn[i] * s;
  if (qfold && (i & 1023) < 256){ s *= ATT_SCALE; t *= ATT_SCALE; }
  scale[i] = s; shift[i] = t;
}

// ---------------- generic NT GEMM, 128x128 tile, BK=32, global_load_lds ----
// LDS layout: unpadded [row][granule(8 halves)] with XOR swizzle slot = g ^ ((row>>1)&3)
// MODE 0: qkv projection, BN epilogue -> row-major bf16 qkv [M][8192]
// MODE 1: PV, *invsum + clamp epilogue -> outc bf16 [G*1024, 4096]
// MODE 2: proj, BN epilogue -> fp32 out rows offset by mbase
template<int MODE>
__launch_bounds__(256, 2)
__global__ void gemm_nt(const unsigned short* __restrict__ A,
                        const unsigned short* __restrict__ Bm,
                        int K, long sA, long sB, long mbase,
                        const float* __restrict__ scale, const float* __restrict__ shift,
                        const float* __restrict__ sums,
                        unsigned short* __restrict__ ob16,
                        float* __restrict__ outf)
{
  __shared__ __align__(16) unsigned short As[4096];
  __shared__ __align__(16) unsigned short Bs[4096];
  const int tid = threadIdx.x;
  const int w = tid >> 6, lane = tid & 63, ln = lane & 31, lg = lane >> 5;
  const int wm = (w >> 1) * 64, wn = (w & 1) * 64;
  const long bm = (long)blockIdx.y * 128, bn = (long)blockIdx.x * 128;
  const int z = blockIdx.z;
  const unsigned short* Ab = A + (long)z * sA + bm * K;
  const unsigned short* Bb = Bm + (long)z * sB + bn * K;

  const int srow0 = w*32 + (lane >> 2);
  const int srow1 = srow0 + 16;
  const int slot  = lane & 3;
  const int ga0 = (slot ^ ((srow0 >> 1) & 3)) * 8;
  const int ga1 = (slot ^ ((srow1 >> 1) & 3)) * 8;
  const unsigned short* gA0 = Ab + (long)srow0 * K + ga0;
  const unsigned short* gA1 = Ab + (long)srow1 * K + ga1;
  const unsigned short* gB0 = Bb + (long)srow0 * K + ga0;
  const unsigned short* gB1 = Bb + (long)srow1 * K + ga1;
  unsigned short* lA0 = As + (w*32)*32;
  unsigned short* lA1 = As + (w*32+16)*32;
  unsigned short* lB0 = Bs + (w*32)*32;
  unsigned short* lB1 = Bs + (w*32+16)*32;

  v16f acc[2][2];
  #pragma unroll
  for (int a = 0; a < 2; a++)
    #pragma unroll
    for (int b = 0; b < 2; b++)
      #pragma unroll
      for (int i = 0; i < 16; i++) acc[a][b][i] = 0.f;

  for (int k0 = 0; k0 < K; k0 += 32){
    __syncthreads();
    glds16(gA0 + k0, lA0);
    glds16(gA1 + k0, lA1);
    glds16(gB0 + k0, lB0);
    glds16(gB1 + k0, lB1);
    __syncthreads();
    #pragma unroll
    for (int kk = 0; kk < 32; kk += 16){
      v8bf af[2], bfr[2];
      #pragma unroll
      for (int t = 0; t < 2; t++){
        int Ra = wm + t*32 + ln;
        int sa = ((kk>>3) + lg) ^ ((Ra >> 1) & 3);
        af[t] = *(const v8bf*)&As[Ra*32 + sa*8];
        int Rb = wn + t*32 + ln;
        int sb = ((kk>>3) + lg) ^ ((Rb >> 1) & 3);
        bfr[t] = *(const v8bf*)&Bs[Rb*32 + sb*8];
      }
      #pragma unroll
      for (int tm = 0; tm < 2; tm++)
        #pragma unroll
        for (int tn = 0; tn < 2; tn++)
          acc[tm][tn] = __builtin_amdgcn_mfma_f32_32x32x16_bf16(af[tm], bfr[tn], acc[tm][tn], 0, 0, 0);
    }
  }

  float invs[2][16];
  if (MODE == 1){
    #pragma unroll
    for (int tm = 0; tm < 2; tm++)
      #pragma unroll
      for (int i = 0; i < 16; i++){
        long gm = bm + wm + tm*32 + (i&3) + 8*(i>>2) + 4*lg;
        invs[tm][i] = 1.0f / sums[(long)z*1024 + gm];
      }
  }

  #pragma unroll
  for (int tm = 0; tm < 2; tm++){
    #pragma unroll
    for (int tn = 0; tn < 2; tn++){
      long gn = bn + wn + tn*32 + ln;
      float sc = 0.f, sh = 0.f;
      if (MODE == 0 || MODE == 2){ sc = scale[gn]; sh = shift[gn]; }
      #pragma unroll
      for (int i = 0; i < 16; i++){
        long gm = bm + wm + tm*32 + (i&3) + 8*(i>>2) + 4*lg;
        float v = acc[tm][tn][i];
        if (MODE == 0){
          ob16[gm*8192 + gn] = f2bf(v * sc + sh);        // row-major, coalesced
        } else if (MODE == 1){
          v = v * invs[tm][i];
          v = fminf(1.f, fmaxf(-1.f, v));
          int b2 = z >> 3, hh = z & 7;
          ob16[((long)b2*1024 + gm)*4096 + hh*512 + gn] = f2bf(v);
        } else {
          outf[(mbase + gm)*512 + gn] = v * sc + sh;
        }
      }
    }
  }
}

// ------- V slice of qkv [row][8192] -> Vt [bh][512][1024] (group-local) ----
__global__ void transpose_v(const unsigned short* __restrict__ qkv,
                            unsigned short* __restrict__ Vt){
  __shared__ __align__(16) unsigned short Ts[64*72];
  const int bh = blockIdx.z;
  const int b2 = bh >> 3, h = bh & 7;
  const int n0 = blockIdx.x * 64, d0 = blockIdx.y * 64;
  const int tid = threadIdx.x;
  const unsigned short* Vb = qkv + (long)b2*1024*8192 + h*1024 + 512;
  unsigned short* Vtb = Vt + (long)bh * 524288;
  #pragma unroll
  for (int i = 0; i < 2; i++){
    int seg = tid + i*256;
    int row = seg >> 3, co = (seg & 7) * 8;
    *(uint4*)&Ts[row*72 + co] = *(const uint4*)(Vb + (long)(n0 + row)*8192 + d0 + co);
  }
  __syncthreads();
  #pragma unroll
  for (int i = 0; i < 2; i++){
    int seg = tid + i*256;
    int drow = seg >> 3, nco = (seg & 7) * 8;
    union { unsigned short s[8]; uint4 u; } r;
    #pragma unroll
    for (int j = 0; j < 8; j++) r.s[j] = Ts[(nco + j)*72 + drow];
    *(uint4*)(Vtb + (long)(d0 + drow)*1024 + n0 + nco) = r.u;
  }
}

// ---------------- attention scores: E = exp(QK^T + bias), row sums ----------
// grid (8, 8G). Block: 4 waves, 128 q-rows (wave w owns rows m0..m0+32).
// K tiles (32 keys x 256) double-buffered in LDS via glds16, shared by all waves.
// Swizzle: LDS slot s of row r holds granule s ^ r (32 granules of 8 halves).
__launch_bounds__(256, 2)
__global__ void attn_scores(const unsigned short* __restrict__ qkv,
                            const float* __restrict__ bias,
                            unsigned short* __restrict__ E,
                            float* __restrict__ sums)
{
  __shared__ __align__(16) unsigned short Ks[2][32*256];
  const int bh = blockIdx.y, mblk = blockIdx.x;
  const int b2 = bh >> 3, h = bh & 7;
  const int tid = threadIdx.x, w = tid >> 6, lane = tid & 63, ln = lane & 31, lg = lane >> 5;
  const int m0 = mblk * 128 + w * 32;
  const unsigned short* qbase = qkv + (long)b2*1024*8192 + h*1024;
  const unsigned short* kbase = qbase + 256;
  const float* biash = bias + (long)h * 1048576;
  unsigned short* Eb = E + (long)bh * 1048576;

  // Q fragments in registers: A[m=ln][k = kf*16 + lg*8 + j]
  v8bf qf[16];
  {
    const unsigned short* qrow = qbase + (long)(m0 + ln)*8192 + lg*8;
    #pragma unroll
    for (int kf = 0; kf < 16; kf++) qf[kf] = ld8(qrow + kf*16);
  }

  const int rr = lane >> 5, slot = lane & 31;   // staging lane split

  float sm[16];
  #pragma unroll
  for (int i = 0; i < 16; i++) sm[i] = 0.f;

  // prologue: stage tile 0 into buffer 0
  #pragma unroll
  for (int j = 0; j < 4; j++){
    int row = w*8 + j*2 + rr;
    glds16(kbase + (long)row*8192 + (slot ^ row)*8, &Ks[0][(w*8 + j*2)*256]);
  }

  for (int t = 0; t < 32; t++){
    __syncthreads();
    const int cb = t & 1;
    if (t < 31){
      const int nb = cb ^ 1;
      #pragma unroll
      for (int j = 0; j < 4; j++){
        int row = w*8 + j*2 + rr;
        glds16(kbase + (long)((t+1)*32 + row)*8192 + (slot ^ row)*8,
               &Ks[nb][(w*8 + j*2)*256]);
      }
    }
    v16f a0, a1;
    #pragma unroll
    for (int i = 0; i < 16; i++){ a0[i] = 0.f; a1[i] = 0.f; }
    #pragma unroll
    for (int kf = 0; kf < 16; kf += 2){
      v8bf k0 = *(const v8bf*)&Ks[cb][ln*256 + ((2*kf   + lg) ^ ln)*8];
      v8bf k1 = *(const v8bf*)&Ks[cb][ln*256 + ((2*kf+2 + lg) ^ ln)*8];
      a0 = __builtin_amdgcn_mfma_f32_32x32x16_bf16(qf[kf],   k0, a0, 0, 0, 0);
      a1 = __builtin_amdgcn_mfma_f32_32x32x16_bf16(qf[kf+1], k1, a1, 0, 0, 0);
    }
    const int col = t*32 + ln;
    #pragma unroll
    for (int q = 0; q < 4; q++){
      #pragma unroll
      for (int j = 0; j < 4; j++){
        int i = q*4 + j;
        int r = 4*lg + 8*q + j;
        float e = __expf(a0[i] + a1[i] + biash[(long)(m0 + r)*1024 + col]);
        sm[i] += e;
        Eb[(long)(m0 + r)*1024 + col] = f2bf(e);
      }
    }
  }

  #pragma unroll
  for (int i = 0; i < 16; i++){
    #pragma unroll
    for (int d = 1; d < 32; d <<= 1) sm[i] += __shfl_xor(sm[i], d, 64);
  }
  if (ln == 0){
    float* sp = sums + (long)bh * 1024 + m0 + 4*lg;
    #pragma unroll
    for (int q = 0; q < 4; q++)
      #pragma unroll
      for (int j = 0; j < 4; j++)
        sp[8*q + j] = sm[q*4 + j];
  }
}

extern "C" void kernel_launch(void* const* d_in, const int* in_sizes, int n_in,
                              void* d_out, int out_size, void* d_ws, size_t ws_size,
                              hipStream_t stream)
{
  const float* x        = (const float*)d_in[0];
  const float* qkv_w    = (const float*)d_in[1];
  const float* qg       = (const float*)d_in[2];
  const float* qb       = (const float*)d_in[3];
  const float* qm       = (const float*)d_in[4];
  const float* qv       = (const float*)d_in[5];
  const float* pos_bias = (const float*)d_in[6];
  const float* pw       = (const float*)d_in[7];
  const float* pg       = (const float*)d_in[8];
  const float* pbt      = (const float*)d_in[9];
  const float* pmn      = (const float*)d_in[10];
  const float* pvr      = (const float*)d_in[11];
  float* out = (float*)d_out;

  // ---- adaptive workspace: FIXED 16.85MB + G*51.94MB ----
  const unsigned long FIXED = 16846848UL;
  const unsigned long PERG  = 51937280UL;
  long G = 1;
  if      (ws_size >= FIXED + PERG*16) G = 16;
  else if (ws_size >= FIXED + PERG*8)  G = 8;
  else if (ws_size >= FIXED + PERG*4)  G = 4;
  else if (ws_size >= FIXED + PERG*2)  G = 2;
  else if (ws_size >= FIXED + PERG)    G = 1;
  else return;

  char* ws = (char*)d_ws;
  unsigned short* wqb = (unsigned short*)(ws + 0L);            // 12,582,912
  unsigned short* wpb = (unsigned short*)(ws + 12582912L);     //  4,194,304
  float* sc_qkv       = (float*)(ws + 16777216L);              //     32,768
  float* sh_qkv       = (float*)(ws + 16809984L);              //     32,768
  float* sc_p         = (float*)(ws + 16842752L);              //      2,048
  float* sh_p         = (float*)(ws + 16844800L);              //      2,048
  const long gb = 16846848L;
  unsigned short* xbg   = (unsigned short*)(ws + gb);                      // G*1,572,864
  unsigned short* qkvg  = (unsigned short*)(ws + gb + G*1572864L);         // G*16,777,216
  unsigned short* Vtg   = (unsigned short*)(ws + gb + G*18350080L);        // G*8,388,608
  unsigned short* Eg    = (unsigned short*)(ws + gb + G*26738688L);        // G*16,777,216
  unsigned short* outcg = (unsigned short*)(ws + gb + G*43515904L);        // G*8,388,608
  float* sumsg          = (float*)(ws + gb + G*51904512L);                 // G*32,768

  // weights + BN affines (once)
  cast_bf16_kernel<<<dim3(3072), 256, 0, stream>>>(qkv_w, wqb, 786432);
  cast_bf16_kernel<<<dim3(1024), 256, 0, stream>>>(pw,    wpb, 262144);
  bn_precompute<<<dim3(32), 256, 0, stream>>>(qg, qb, qm, qv, sc_qkv, sh_qkv, 8192, 1);
  bn_precompute<<<dim3(2),  256, 0, stream>>>(pg, pbt, pmn, pvr, sc_p, sh_p, 512, 0);

  const int nG = (int)(16 / G);
  for (int g = 0; g < nG; g++){
    const float* xg = x + (long)g * G * 786432L;
    long mbase = (long)g * G * 1024L;

    cast_bf16_kernel<<<dim3((unsigned)(G*384)), 256, 0, stream>>>(xg, xbg, (int)(G*98304));

    // qkv = BN(x @ qkv_w^T) -> row-major [G*1024][8192]
    gemm_nt<0><<<dim3(64, (unsigned)(8*G), 1), 256, 0, stream>>>(
        xbg, wqb, 768, 0L, 0L, 0L, sc_qkv, sh_qkv, nullptr, qkvg, nullptr);

    // V slice -> Vt [bh][512][1024]
    transpose_v<<<dim3(16, 8, (unsigned)(8*G)), 256, 0, stream>>>(qkvg, Vtg);

    // E = exp(QK^T + bias), rowsums
    attn_scores<<<dim3(8, (unsigned)(8*G)), 256, 0, stream>>>(qkvg, pos_bias, Eg, sumsg);

    // outc = clamp((E @ V) / sum, -1, 1)
    gemm_nt<1><<<dim3(4, 8, (unsigned)(8*G)), 256, 0, stream>>>(
        Eg, Vtg, 1024, 1048576L, 524288L, 0L, nullptr, nullptr, sumsg, outcg, nullptr);

    // out rows [mbase, mbase+G*1024) = BN(outc @ proj_w^T)
    gemm_nt<2><<<dim3(4, (unsigned)(8*G), 1), 256, 0, stream>>>(
        outcg, wpb, 4096, 0L, 0L, mbase, sc_p, sh_p, nullptr, nullptr, out);
  }
}

// Round 5
// 1126.629 us; speedup vs baseline: 1.4683x; 1.1648x over previous
//
#include <hip/hip_runtime.h>

using v8bf  = __bf16 __attribute__((ext_vector_type(8)));
using v16f  = float  __attribute__((ext_vector_type(16)));

#define EPS_BN 1e-5f
#define ATT_SCALE 0.044194173824159216f   // 512^-0.5

__device__ __forceinline__ unsigned short f2bf(float f){
  union { float f; unsigned int u; } c; c.f = f;
  unsigned int u = c.u + 0x7fffu + ((c.u >> 16) & 1u);
  return (unsigned short)(u >> 16);
}

__device__ __forceinline__ v8bf ld8(const unsigned short* p){
  union { uint4 u; v8bf v; } c;
  c.u = *(const uint4*)p;
  return c.v;
}

// async global->LDS, 16B per lane; LDS dest = uniform base + lane*16
__device__ __forceinline__ void glds16(const unsigned short* g, unsigned short* l){
  __builtin_amdgcn_global_load_lds(
      (const __attribute__((address_space(1))) void*)g,
      (__attribute__((address_space(3))) void*)l, 16, 0, 0);
}

// ---------------- cast fp32 -> bf16 (8 elems/thread) ----------------
__global__ void cast_bf16_kernel(const float* __restrict__ src,
                                 unsigned short* __restrict__ dst, int n8){
  int i = blockIdx.x * 256 + threadIdx.x;
  if (i >= n8) return;
  const float4* s4 = (const float4*)src;
  float4 a = s4[2*i], b = s4[2*i+1];
  union { unsigned short s[8]; uint4 u; } r;
  r.s[0]=f2bf(a.x); r.s[1]=f2bf(a.y); r.s[2]=f2bf(a.z); r.s[3]=f2bf(a.w);
  r.s[4]=f2bf(b.x); r.s[5]=f2bf(b.y); r.s[6]=f2bf(b.z); r.s[7]=f2bf(b.w);
  ((uint4*)dst)[i] = r.u;
}

// ---------------- BN affine precompute ----------------
__global__ void bn_precompute(const float* __restrict__ g, const float* __restrict__ be,
                              const float* __restrict__ mn, const float* __restrict__ vr,
                              float* __restrict__ scale, float* __restrict__ shift,
                              int n, int qfold){
  int i = blockIdx.x * 256 + threadIdx.x;
  if (i >= n) return;
  float s = g[i] * rsqrtf(vr[i] + EPS_BN);
  float t = be[i] - mn[i] * s;
  if (qfold && (i & 1023) < 256){ s *= ATT_SCALE; t *= ATT_SCALE; }
  scale[i] = s; shift[i] = t;
}

// ---------------- generic NT GEMM, 128x128 tile, BK=32, global_load_lds ----
// LDS layout: unpadded [row][granule(8 halves)] with XOR swizzle slot = g ^ ((row>>1)&3)
// MODE 0: qkv projection, BN epilogue -> row-major bf16 qkv [M][8192]
// MODE 1: PV, *invsum + clamp epilogue -> outc bf16 [G*1024, 4096]
// MODE 3: proj split-K (blockIdx.z = split of 4) -> fp32 partials [4][Mtot][512]
template<int MODE>
__launch_bounds__(256, 2)
__global__ void gemm_nt(const unsigned short* __restrict__ A,
                        const unsigned short* __restrict__ Bm,
                        int K, long sA, long sB, long mbase,   // mbase = Mtot for MODE 3
                        const float* __restrict__ scale, const float* __restrict__ shift,
                        const float* __restrict__ sums,
                        unsigned short* __restrict__ ob16,
                        float* __restrict__ outf)
{
  __shared__ __align__(16) unsigned short As[4096];
  __shared__ __align__(16) unsigned short Bs[4096];
  const int tid = threadIdx.x;
  const int w = tid >> 6, lane = tid & 63, ln = lane & 31, lg = lane >> 5;
  const int wm = (w >> 1) * 64, wn = (w & 1) * 64;
  const long bm = (long)blockIdx.y * 128, bn = (long)blockIdx.x * 128;
  const int z = blockIdx.z;
  const unsigned short* Ab = A + (MODE == 3 ? 0L : (long)z * sA) + bm * K;
  const unsigned short* Bb = Bm + (MODE == 3 ? 0L : (long)z * sB) + bn * K;

  const int kbeg = (MODE == 3) ? z * (K >> 2) : 0;
  const int kend = (MODE == 3) ? kbeg + (K >> 2) : K;

  const int srow0 = w*32 + (lane >> 2);
  const int srow1 = srow0 + 16;
  const int slot  = lane & 3;
  const int ga0 = (slot ^ ((srow0 >> 1) & 3)) * 8;
  const int ga1 = (slot ^ ((srow1 >> 1) & 3)) * 8;
  const unsigned short* gA0 = Ab + (long)srow0 * K + ga0;
  const unsigned short* gA1 = Ab + (long)srow1 * K + ga1;
  const unsigned short* gB0 = Bb + (long)srow0 * K + ga0;
  const unsigned short* gB1 = Bb + (long)srow1 * K + ga1;
  unsigned short* lA0 = As + (w*32)*32;
  unsigned short* lA1 = As + (w*32+16)*32;
  unsigned short* lB0 = Bs + (w*32)*32;
  unsigned short* lB1 = Bs + (w*32+16)*32;

  v16f acc[2][2];
  #pragma unroll
  for (int a = 0; a < 2; a++)
    #pragma unroll
    for (int b = 0; b < 2; b++)
      #pragma unroll
      for (int i = 0; i < 16; i++) acc[a][b][i] = 0.f;

  for (int k0 = kbeg; k0 < kend; k0 += 32){
    __syncthreads();
    glds16(gA0 + k0, lA0);
    glds16(gA1 + k0, lA1);
    glds16(gB0 + k0, lB0);
    glds16(gB1 + k0, lB1);
    __syncthreads();
    #pragma unroll
    for (int kk = 0; kk < 32; kk += 16){
      v8bf af[2], bfr[2];
      #pragma unroll
      for (int t = 0; t < 2; t++){
        int Ra = wm + t*32 + ln;
        int sa = ((kk>>3) + lg) ^ ((Ra >> 1) & 3);
        af[t] = *(const v8bf*)&As[Ra*32 + sa*8];
        int Rb = wn + t*32 + ln;
        int sb = ((kk>>3) + lg) ^ ((Rb >> 1) & 3);
        bfr[t] = *(const v8bf*)&Bs[Rb*32 + sb*8];
      }
      #pragma unroll
      for (int tm = 0; tm < 2; tm++)
        #pragma unroll
        for (int tn = 0; tn < 2; tn++)
          acc[tm][tn] = __builtin_amdgcn_mfma_f32_32x32x16_bf16(af[tm], bfr[tn], acc[tm][tn], 0, 0, 0);
    }
  }

  float invs[2][16];
  if (MODE == 1){
    #pragma unroll
    for (int tm = 0; tm < 2; tm++)
      #pragma unroll
      for (int i = 0; i < 16; i++){
        long gm = bm + wm + tm*32 + (i&3) + 8*(i>>2) + 4*lg;
        invs[tm][i] = 1.0f / sums[(long)z*1024 + gm];
      }
  }

  #pragma unroll
  for (int tm = 0; tm < 2; tm++){
    #pragma unroll
    for (int tn = 0; tn < 2; tn++){
      long gn = bn + wn + tn*32 + ln;
      float sc = 0.f, sh = 0.f;
      if (MODE == 0){ sc = scale[gn]; sh = shift[gn]; }
      #pragma unroll
      for (int i = 0; i < 16; i++){
        long gm = bm + wm + tm*32 + (i&3) + 8*(i>>2) + 4*lg;
        float v = acc[tm][tn][i];
        if (MODE == 0){
          ob16[gm*8192 + gn] = f2bf(v * sc + sh);        // row-major, coalesced
        } else if (MODE == 1){
          v = v * invs[tm][i];
          v = fminf(1.f, fmaxf(-1.f, v));
          int b2 = z >> 3, hh = z & 7;
          ob16[((long)b2*1024 + gm)*4096 + hh*512 + gn] = f2bf(v);
        } else {
          outf[((long)z * mbase + gm)*512 + gn] = v;     // fp32 partial
        }
      }
    }
  }
}

// -------- reduce 4 split-K partials + BN affine -> fp32 out rows ----------
__global__ void reduce_bn(const float* __restrict__ part,
                          const float* __restrict__ sc, const float* __restrict__ sh,
                          float* __restrict__ out, long Mtot, long mbase){
  long idx = (long)blockIdx.x * 256 + threadIdx.x;     // float4 index
  if (idx >= Mtot * 128) return;
  long gm = idx >> 7;
  int gn4 = (int)(idx & 127) * 4;
  long PS = Mtot * 512;
  const float* p = part + gm*512 + gn4;
  float4 p0 = *(const float4*)(p);
  float4 p1 = *(const float4*)(p + PS);
  float4 p2 = *(const float4*)(p + 2*PS);
  float4 p3 = *(const float4*)(p + 3*PS);
  float4 s4 = *(const float4*)(sc + gn4);
  float4 h4 = *(const float4*)(sh + gn4);
  float4 r;
  r.x = (p0.x+p1.x+p2.x+p3.x)*s4.x + h4.x;
  r.y = (p0.y+p1.y+p2.y+p3.y)*s4.y + h4.y;
  r.z = (p0.z+p1.z+p2.z+p3.z)*s4.z + h4.z;
  r.w = (p0.w+p1.w+p2.w+p3.w)*s4.w + h4.w;
  *(float4*)(out + (mbase + gm)*512 + gn4) = r;
}

// ------- V slice of qkv [row][8192] -> Vt [bh][512][1024] (group-local) ----
__global__ void transpose_v(const unsigned short* __restrict__ qkv,
                            unsigned short* __restrict__ Vt){
  __shared__ __align__(16) unsigned short Ts[64*72];
  const int bh = blockIdx.z;
  const int b2 = bh >> 3, h = bh & 7;
  const int n0 = blockIdx.x * 64, d0 = blockIdx.y * 64;
  const int tid = threadIdx.x;
  const unsigned short* Vb = qkv + (long)b2*1024*8192 + h*1024 + 512;
  unsigned short* Vtb = Vt + (long)bh * 524288;
  #pragma unroll
  for (int i = 0; i < 2; i++){
    int seg = tid + i*256;
    int row = seg >> 3, co = (seg & 7) * 8;
    *(uint4*)&Ts[row*72 + co] = *(const uint4*)(Vb + (long)(n0 + row)*8192 + d0 + co);
  }
  __syncthreads();
  #pragma unroll
  for (int i = 0; i < 2; i++){
    int seg = tid + i*256;
    int drow = seg >> 3, nco = (seg & 7) * 8;
    union { unsigned short s[8]; uint4 u; } r;
    #pragma unroll
    for (int j = 0; j < 8; j++) r.s[j] = Ts[(nco + j)*72 + drow];
    *(uint4*)(Vtb + (long)(d0 + drow)*1024 + n0 + nco) = r.u;
  }
}

// ---------------- attention scores: E = exp(QK^T + bias), row sums ----------
// grid (8, 8G). Block: 4 waves, 128 q-rows (wave w owns rows m0..m0+32).
// K tiles (32 keys x 256) double-buffered in LDS via glds16, shared by all waves.
__launch_bounds__(256, 2)
__global__ void attn_scores(const unsigned short* __restrict__ qkv,
                            const float* __restrict__ bias,
                            unsigned short* __restrict__ E,
                            float* __restrict__ sums)
{
  __shared__ __align__(16) unsigned short Ks[2][32*256];
  const int bh = blockIdx.y, mblk = blockIdx.x;
  const int b2 = bh >> 3, h = bh & 7;
  const int tid = threadIdx.x, w = tid >> 6, lane = tid & 63, ln = lane & 31, lg = lane >> 5;
  const int m0 = mblk * 128 + w * 32;
  const unsigned short* qbase = qkv + (long)b2*1024*8192 + h*1024;
  const unsigned short* kbase = qbase + 256;
  const float* biash = bias + (long)h * 1048576;
  unsigned short* Eb = E + (long)bh * 1048576;

  v8bf qf[16];
  {
    const unsigned short* qrow = qbase + (long)(m0 + ln)*8192 + lg*8;
    #pragma unroll
    for (int kf = 0; kf < 16; kf++) qf[kf] = ld8(qrow + kf*16);
  }

  const int rr = lane >> 5, slot = lane & 31;

  float sm[16];
  #pragma unroll
  for (int i = 0; i < 16; i++) sm[i] = 0.f;

  #pragma unroll
  for (int j = 0; j < 4; j++){
    int row = w*8 + j*2 + rr;
    glds16(kbase + (long)row*8192 + (slot ^ row)*8, &Ks[0][(w*8 + j*2)*256]);
  }

  for (int t = 0; t < 32; t++){
    __syncthreads();
    const int cb = t & 1;
    if (t < 31){
      const int nb = cb ^ 1;
      #pragma unroll
      for (int j = 0; j < 4; j++){
        int row = w*8 + j*2 + rr;
        glds16(kbase + (long)((t+1)*32 + row)*8192 + (slot ^ row)*8,
               &Ks[nb][(w*8 + j*2)*256]);
      }
    }
    v16f a0, a1;
    #pragma unroll
    for (int i = 0; i < 16; i++){ a0[i] = 0.f; a1[i] = 0.f; }
    #pragma unroll
    for (int kf = 0; kf < 16; kf += 2){
      v8bf k0 = *(const v8bf*)&Ks[cb][ln*256 + ((2*kf   + lg) ^ ln)*8];
      v8bf k1 = *(const v8bf*)&Ks[cb][ln*256 + ((2*kf+2 + lg) ^ ln)*8];
      a0 = __builtin_amdgcn_mfma_f32_32x32x16_bf16(qf[kf],   k0, a0, 0, 0, 0);
      a1 = __builtin_amdgcn_mfma_f32_32x32x16_bf16(qf[kf+1], k1, a1, 0, 0, 0);
    }
    const int col = t*32 + ln;
    #pragma unroll
    for (int q = 0; q < 4; q++){
      #pragma unroll
      for (int j = 0; j < 4; j++){
        int i = q*4 + j;
        int r = 4*lg + 8*q + j;
        float e = __expf(a0[i] + a1[i] + biash[(long)(m0 + r)*1024 + col]);
        sm[i] += e;
        Eb[(long)(m0 + r)*1024 + col] = f2bf(e);
      }
    }
  }

  #pragma unroll
  for (int i = 0; i < 16; i++){
    #pragma unroll
    for (int d = 1; d < 32; d <<= 1) sm[i] += __shfl_xor(sm[i], d, 64);
  }
  if (ln == 0){
    float* sp = sums + (long)bh * 1024 + m0 + 4*lg;
    #pragma unroll
    for (int q = 0; q < 4; q++)
      #pragma unroll
      for (int j = 0; j < 4; j++)
        sp[8*q + j] = sm[q*4 + j];
  }
}

extern "C" void kernel_launch(void* const* d_in, const int* in_sizes, int n_in,
                              void* d_out, int out_size, void* d_ws, size_t ws_size,
                              hipStream_t stream)
{
  const float* x        = (const float*)d_in[0];
  const float* qkv_w    = (const float*)d_in[1];
  const float* qg       = (const float*)d_in[2];
  const float* qb       = (const float*)d_in[3];
  const float* qm       = (const float*)d_in[4];
  const float* qv       = (const float*)d_in[5];
  const float* pos_bias = (const float*)d_in[6];
  const float* pw       = (const float*)d_in[7];
  const float* pg       = (const float*)d_in[8];
  const float* pbt      = (const float*)d_in[9];
  const float* pmn      = (const float*)d_in[10];
  const float* pvr      = (const float*)d_in[11];
  float* out = (float*)d_out;

  // ---- adaptive workspace: FIXED 16.85MB + G*43.55MB (outc/partials overlaid) ----
  const unsigned long FIXED = 16846848UL;
  const unsigned long PERG  = 43548672UL;
  long G = 1;
  if      (ws_size >= FIXED + PERG*16) G = 16;
  else if (ws_size >= FIXED + PERG*8)  G = 8;
  else if (ws_size >= FIXED + PERG*4)  G = 4;
  else if (ws_size >= FIXED + PERG*2)  G = 2;
  else if (ws_size >= FIXED + PERG)    G = 1;
  else return;

  char* ws = (char*)d_ws;
  unsigned short* wqb = (unsigned short*)(ws + 0L);            // 12,582,912
  unsigned short* wpb = (unsigned short*)(ws + 12582912L);     //  4,194,304
  float* sc_qkv       = (float*)(ws + 16777216L);              //     32,768
  float* sh_qkv       = (float*)(ws + 16809984L);              //     32,768
  float* sc_p         = (float*)(ws + 16842752L);              //      2,048
  float* sh_p         = (float*)(ws + 16844800L);              //      2,048
  const long gb = 16846848L;
  unsigned short* xbg   = (unsigned short*)(ws + gb);                      // G*1,572,864
  unsigned short* qkvg  = (unsigned short*)(ws + gb + G*1572864L);         // G*16,777,216
  unsigned short* Vtg   = (unsigned short*)(ws + gb + G*18350080L);        // G*8,388,608
  unsigned short* Eg    = (unsigned short*)(ws + gb + G*26738688L);        // G*16,777,216
  float* sumsg          = (float*)(ws + gb + G*43515904L);                 // G*32,768
  // overlays (dead-buffer reuse):
  unsigned short* outcg = qkvg;                 // G*8,388,608 <= qkv region (dead after attn)
  float* partials       = (float*)Eg;           // G*8,388,608 <= E region (dead after PV)

  // weights + BN affines (once)
  cast_bf16_kernel<<<dim3(3072), 256, 0, stream>>>(qkv_w, wqb, 786432);
  cast_bf16_kernel<<<dim3(1024), 256, 0, stream>>>(pw,    wpb, 262144);
  bn_precompute<<<dim3(32), 256, 0, stream>>>(qg, qb, qm, qv, sc_qkv, sh_qkv, 8192, 1);
  bn_precompute<<<dim3(2),  256, 0, stream>>>(pg, pbt, pmn, pvr, sc_p, sh_p, 512, 0);

  const int nG = (int)(16 / G);
  for (int g = 0; g < nG; g++){
    const float* xg = x + (long)g * G * 786432L;
    long mbase = (long)g * G * 1024L;

    cast_bf16_kernel<<<dim3((unsigned)(G*384)), 256, 0, stream>>>(xg, xbg, (int)(G*98304));

    // qkv = BN(x @ qkv_w^T) -> row-major [G*1024][8192]
    gemm_nt<0><<<dim3(64, (unsigned)(8*G), 1), 256, 0, stream>>>(
        xbg, wqb, 768, 0L, 0L, 0L, sc_qkv, sh_qkv, nullptr, qkvg, nullptr);

    // V slice -> Vt [bh][512][1024]
    transpose_v<<<dim3(16, 8, (unsigned)(8*G)), 256, 0, stream>>>(qkvg, Vtg);

    // E = exp(QK^T + bias), rowsums
    attn_scores<<<dim3(8, (unsigned)(8*G)), 256, 0, stream>>>(qkvg, pos_bias, Eg, sumsg);

    // outc = clamp((E @ V) / sum, -1, 1)  (overlays qkv region)
    gemm_nt<1><<<dim3(4, 8, (unsigned)(8*G)), 256, 0, stream>>>(
        Eg, Vtg, 1024, 1048576L, 524288L, 0L, nullptr, nullptr, sumsg, outcg, nullptr);

    // proj split-K=4 -> fp32 partials (overlays E region)
    gemm_nt<3><<<dim3(4, (unsigned)(8*G), 4), 256, 0, stream>>>(
        outcg, wpb, 4096, 0L, 0L, (long)(G*1024), nullptr, nullptr, nullptr,
        nullptr, partials);

    // out rows [mbase, ...) = (sum partials)*sc + sh
    reduce_bn<<<dim3((unsigned)(G*512)), 256, 0, stream>>>(
        partials, sc_p, sh_p, out, (long)(G*1024), mbase);
  }
}

// Round 6
// 1062.910 us; speedup vs baseline: 1.5564x; 1.0599x over previous
//
#include <hip/hip_runtime.h>

using v8bf  = __bf16 __attribute__((ext_vector_type(8)));
using v16f  = float  __attribute__((ext_vector_type(16)));

#define EPS_BN 1e-5f
#define ATT_SCALE 0.044194173824159216f   // 512^-0.5

__device__ __forceinline__ unsigned short f2bf(float f){
  union { float f; unsigned int u; } c; c.f = f;
  unsigned int u = c.u + 0x7fffu + ((c.u >> 16) & 1u);
  return (unsigned short)(u >> 16);
}

__device__ __forceinline__ v8bf ld8(const unsigned short* p){
  union { uint4 u; v8bf v; } c;
  c.u = *(const uint4*)p;
  return c.v;
}

// async global->LDS, 16B per lane; LDS dest = uniform base + lane*16
__device__ __forceinline__ void glds16(const unsigned short* g, unsigned short* l){
  __builtin_amdgcn_global_load_lds(
      (const __attribute__((address_space(1))) void*)g,
      (__attribute__((address_space(3))) void*)l, 16, 0, 0);
}

// ---------------- cast fp32 -> bf16 (8 elems/thread) ----------------
__global__ void cast_bf16_kernel(const float* __restrict__ src,
                                 unsigned short* __restrict__ dst, int n8){
  int i = blockIdx.x * 256 + threadIdx.x;
  if (i >= n8) return;
  const float4* s4 = (const float4*)src;
  float4 a = s4[2*i], b = s4[2*i+1];
  union { unsigned short s[8]; uint4 u; } r;
  r.s[0]=f2bf(a.x); r.s[1]=f2bf(a.y); r.s[2]=f2bf(a.z); r.s[3]=f2bf(a.w);
  r.s[4]=f2bf(b.x); r.s[5]=f2bf(b.y); r.s[6]=f2bf(b.z); r.s[7]=f2bf(b.w);
  ((uint4*)dst)[i] = r.u;
}

// ---------------- BN affine precompute ----------------
__global__ void bn_precompute(const float* __restrict__ g, const float* __restrict__ be,
                              const float* __restrict__ mn, const float* __restrict__ vr,
                              float* __restrict__ scale, float* __restrict__ shift,
                              int n, int qfold){
  int i = blockIdx.x * 256 + threadIdx.x;
  if (i >= n) return;
  float s = g[i] * rsqrtf(vr[i] + EPS_BN);
  float t = be[i] - mn[i] * s;
  if (qfold && (i & 1023) < 256){ s *= ATT_SCALE; t *= ATT_SCALE; }
  scale[i] = s; shift[i] = t;
}

// ---------------- generic NT GEMM, 128x128 tile, BK=64, global_load_lds ----
// LDS: [row][8 granules of 8 halves], slot s of row r holds granule s ^ (r&7)
// MODE 0: qkv projection, BN epilogue -> row-major bf16 qkv [M][8192]
// MODE 1: PV, *invsum + clamp epilogue -> outc bf16 [G*1024, 4096]
// MODE 3: proj split-K (blockIdx.z = split of 4) -> fp32 partials [4][Mtot][512]
template<int MODE>
__launch_bounds__(256, 2)
__global__ void gemm_nt(const unsigned short* __restrict__ A,
                        const unsigned short* __restrict__ Bm,
                        int K, long sA, long sB, long mbase,   // mbase = Mtot for MODE 3
                        const float* __restrict__ scale, const float* __restrict__ shift,
                        const float* __restrict__ sums,
                        unsigned short* __restrict__ ob16,
                        float* __restrict__ outf)
{
  __shared__ __align__(16) unsigned short As[8192];   // 128 x 64
  __shared__ __align__(16) unsigned short Bs[8192];
  const int tid = threadIdx.x;
  const int w = tid >> 6, lane = tid & 63, ln = lane & 31, lg = lane >> 5;
  const int wm = (w >> 1) * 64, wn = (w & 1) * 64;
  const long bm = (long)blockIdx.y * 128, bn = (long)blockIdx.x * 128;
  const int z = blockIdx.z;
  const unsigned short* Ab = A + (MODE == 3 ? 0L : (long)z * sA) + bm * K;
  const unsigned short* Bb = Bm + (MODE == 3 ? 0L : (long)z * sB) + bn * K;

  const int kbeg = (MODE == 3) ? z * (K >> 2) : 0;
  const int kend = (MODE == 3) ? kbeg + (K >> 2) : K;

  // staging: wave w covers tile rows [w*32, w*32+32), 4 instrs/matrix (8 rows each)
  const int rsub = lane >> 3;            // 0..7
  const int gsl  = lane & 7;             // granule slot 0..7
  const unsigned short* gA[4]; const unsigned short* gB[4];
  unsigned short *lA[4], *lB[4];
  #pragma unroll
  for (int i = 0; i < 4; i++){
    int r = w*32 + i*8 + rsub;
    int go = (gsl ^ (r & 7)) * 8;        // global granule offset (halves)
    gA[i] = Ab + (long)r * K + go;
    gB[i] = Bb + (long)r * K + go;
    lA[i] = As + (w*32 + i*8) * 64;
    lB[i] = Bs + (w*32 + i*8) * 64;
  }

  v16f acc[2][2];
  #pragma unroll
  for (int a = 0; a < 2; a++)
    #pragma unroll
    for (int b = 0; b < 2; b++)
      #pragma unroll
      for (int i = 0; i < 16; i++) acc[a][b][i] = 0.f;

  for (int k0 = kbeg; k0 < kend; k0 += 64){
    __syncthreads();
    #pragma unroll
    for (int i = 0; i < 4; i++){
      glds16(gA[i] + k0, lA[i]);
      glds16(gB[i] + k0, lB[i]);
    }
    __syncthreads();
    #pragma unroll
    for (int kk = 0; kk < 4; kk++){     // granule-pair index: gd = kk*2 + lg
      v8bf af[2], bfr[2];
      #pragma unroll
      for (int t = 0; t < 2; t++){
        int Ra = wm + t*32 + ln;
        af[t] = *(const v8bf*)&As[Ra*64 + ((kk*2 + lg) ^ (Ra & 7))*8];
        int Rb = wn + t*32 + ln;
        bfr[t] = *(const v8bf*)&Bs[Rb*64 + ((kk*2 + lg) ^ (Rb & 7))*8];
      }
      #pragma unroll
      for (int tm = 0; tm < 2; tm++)
        #pragma unroll
        for (int tn = 0; tn < 2; tn++)
          acc[tm][tn] = __builtin_amdgcn_mfma_f32_32x32x16_bf16(af[tm], bfr[tn], acc[tm][tn], 0, 0, 0);
    }
  }

  float invs[2][16];
  if (MODE == 1){
    #pragma unroll
    for (int tm = 0; tm < 2; tm++)
      #pragma unroll
      for (int i = 0; i < 16; i++){
        long gm = bm + wm + tm*32 + (i&3) + 8*(i>>2) + 4*lg;
        invs[tm][i] = 1.0f / sums[(long)z*1024 + gm];
      }
  }

  #pragma unroll
  for (int tm = 0; tm < 2; tm++){
    #pragma unroll
    for (int tn = 0; tn < 2; tn++){
      long gn = bn + wn + tn*32 + ln;
      float sc = 0.f, sh = 0.f;
      if (MODE == 0){ sc = scale[gn]; sh = shift[gn]; }
      #pragma unroll
      for (int i = 0; i < 16; i++){
        long gm = bm + wm + tm*32 + (i&3) + 8*(i>>2) + 4*lg;
        float v = acc[tm][tn][i];
        if (MODE == 0){
          ob16[gm*8192 + gn] = f2bf(v * sc + sh);        // row-major, coalesced
        } else if (MODE == 1){
          v = v * invs[tm][i];
          v = fminf(1.f, fmaxf(-1.f, v));
          int b2 = z >> 3, hh = z & 7;
          ob16[((long)b2*1024 + gm)*4096 + hh*512 + gn] = f2bf(v);
        } else {
          outf[((long)z * mbase + gm)*512 + gn] = v;     // fp32 partial
        }
      }
    }
  }
}

// -------- reduce 4 split-K partials + BN affine -> fp32 out rows ----------
__global__ void reduce_bn(const float* __restrict__ part,
                          const float* __restrict__ sc, const float* __restrict__ sh,
                          float* __restrict__ out, long Mtot, long mbase){
  long idx = (long)blockIdx.x * 256 + threadIdx.x;     // float4 index
  if (idx >= Mtot * 128) return;
  long gm = idx >> 7;
  int gn4 = (int)(idx & 127) * 4;
  long PS = Mtot * 512;
  const float* p = part + gm*512 + gn4;
  float4 p0 = *(const float4*)(p);
  float4 p1 = *(const float4*)(p + PS);
  float4 p2 = *(const float4*)(p + 2*PS);
  float4 p3 = *(const float4*)(p + 3*PS);
  float4 s4 = *(const float4*)(sc + gn4);
  float4 h4 = *(const float4*)(sh + gn4);
  float4 r;
  r.x = (p0.x+p1.x+p2.x+p3.x)*s4.x + h4.x;
  r.y = (p0.y+p1.y+p2.y+p3.y)*s4.y + h4.y;
  r.z = (p0.z+p1.z+p2.z+p3.z)*s4.z + h4.z;
  r.w = (p0.w+p1.w+p2.w+p3.w)*s4.w + h4.w;
  *(float4*)(out + (mbase + gm)*512 + gn4) = r;
}

// ------- V slice of qkv [row][8192] -> Vt [bh][512][1024] (group-local) ----
__global__ void transpose_v(const unsigned short* __restrict__ qkv,
                            unsigned short* __restrict__ Vt){
  __shared__ __align__(16) unsigned short Ts[64*72];
  const int bh = blockIdx.z;
  const int b2 = bh >> 3, h = bh & 7;
  const int n0 = blockIdx.x * 64, d0 = blockIdx.y * 64;
  const int tid = threadIdx.x;
  const unsigned short* Vb = qkv + (long)b2*1024*8192 + h*1024 + 512;
  unsigned short* Vtb = Vt + (long)bh * 524288;
  #pragma unroll
  for (int i = 0; i < 2; i++){
    int seg = tid + i*256;
    int row = seg >> 3, co = (seg & 7) * 8;
    *(uint4*)&Ts[row*72 + co] = *(const uint4*)(Vb + (long)(n0 + row)*8192 + d0 + co);
  }
  __syncthreads();
  #pragma unroll
  for (int i = 0; i < 2; i++){
    int seg = tid + i*256;
    int drow = seg >> 3, nco = (seg & 7) * 8;
    union { unsigned short s[8]; uint4 u; } r;
    #pragma unroll
    for (int j = 0; j < 8; j++) r.s[j] = Ts[(nco + j)*72 + drow];
    *(uint4*)(Vtb + (long)(d0 + drow)*1024 + n0 + nco) = r.u;
  }
}

// ---------------- attention scores: E = exp(QK^T + bias), row sums ----------
// grid (16, 8G). Block: 128 thr (2 waves), 64 q-rows; wave w owns rows m0..m0+32
// and sweeps ALL 1024 keys. K tiles (32 keys x 256) double-buffered in LDS,
// staged cooperatively, shared by both waves. No cross-wave reduction needed.
__launch_bounds__(128, 2)
__global__ void attn_scores(const unsigned short* __restrict__ qkv,
                            const float* __restrict__ bias,
                            unsigned short* __restrict__ E,
                            float* __restrict__ sums)
{
  __shared__ __align__(16) unsigned short Ks[2][32*256];   // 2 x 16 KB
  const int bh = blockIdx.y, mblk = blockIdx.x;
  const int b2 = bh >> 3, h = bh & 7;
  const int tid = threadIdx.x, w = tid >> 6, lane = tid & 63, ln = lane & 31, lg = lane >> 5;
  const int m0 = mblk * 64 + w * 32;
  const unsigned short* qbase = qkv + (long)b2*1024*8192 + h*1024;
  const unsigned short* kbase = qbase + 256;
  const float* biash = bias + (long)h * 1048576;
  unsigned short* Eb = E + (long)bh * 1048576;

  // Q fragments: A[m=ln][k = kf*16 + lg*8 + j]
  v8bf qf[16];
  {
    const unsigned short* qrow = qbase + (long)(m0 + ln)*8192 + lg*8;
    #pragma unroll
    for (int kf = 0; kf < 16; kf++) qf[kf] = ld8(qrow + kf*16);
  }

  const int rr = lane >> 5, slot = lane & 31;   // staging split: 2 rows/instr

  float sm[16];
  #pragma unroll
  for (int i = 0; i < 16; i++) sm[i] = 0.f;

  // prologue: stage tile 0 into buffer 0 (wave w stages rows [w*16, w*16+16))
  #pragma unroll
  for (int i = 0; i < 8; i++){
    int row = w*16 + i*2 + rr;
    glds16(kbase + (long)row*8192 + (slot ^ row)*8, &Ks[0][(w*16 + i*2)*256]);
  }

  for (int t = 0; t < 32; t++){
    __syncthreads();
    const int cb = t & 1;
    if (t < 31){
      const int nb = cb ^ 1;
      #pragma unroll
      for (int i = 0; i < 8; i++){
        int row = w*16 + i*2 + rr;
        glds16(kbase + (long)((t+1)*32 + row)*8192 + (slot ^ row)*8,
               &Ks[nb][(w*16 + i*2)*256]);
      }
    }
    v16f a0, a1;
    #pragma unroll
    for (int i = 0; i < 16; i++){ a0[i] = 0.f; a1[i] = 0.f; }
    #pragma unroll
    for (int kf = 0; kf < 16; kf += 2){
      v8bf k0 = *(const v8bf*)&Ks[cb][ln*256 + ((2*kf   + lg) ^ ln)*8];
      v8bf k1 = *(const v8bf*)&Ks[cb][ln*256 + ((2*kf+2 + lg) ^ ln)*8];
      a0 = __builtin_amdgcn_mfma_f32_32x32x16_bf16(qf[kf],   k0, a0, 0, 0, 0);
      a1 = __builtin_amdgcn_mfma_f32_32x32x16_bf16(qf[kf+1], k1, a1, 0, 0, 0);
    }
    const int col = t*32 + ln;
    #pragma unroll
    for (int q = 0; q < 4; q++){
      #pragma unroll
      for (int j = 0; j < 4; j++){
        int i = q*4 + j;
        int r = 4*lg + 8*q + j;
        float e = __expf(a0[i] + a1[i] + biash[(long)(m0 + r)*1024 + col]);
        sm[i] += e;
        Eb[(long)(m0 + r)*1024 + col] = f2bf(e);
      }
    }
  }

  // each wave owns its 32 rows entirely: reduce across the 32 key-lanes only
  #pragma unroll
  for (int i = 0; i < 16; i++){
    #pragma unroll
    for (int d = 1; d < 32; d <<= 1) sm[i] += __shfl_xor(sm[i], d, 64);
  }
  if (ln == 0){
    float* sp = sums + (long)bh * 1024 + m0 + 4*lg;
    #pragma unroll
    for (int q = 0; q < 4; q++)
      #pragma unroll
      for (int j = 0; j < 4; j++)
        sp[8*q + j] = sm[q*4 + j];
  }
}

extern "C" void kernel_launch(void* const* d_in, const int* in_sizes, int n_in,
                              void* d_out, int out_size, void* d_ws, size_t ws_size,
                              hipStream_t stream)
{
  const float* x        = (const float*)d_in[0];
  const float* qkv_w    = (const float*)d_in[1];
  const float* qg       = (const float*)d_in[2];
  const float* qb       = (const float*)d_in[3];
  const float* qm       = (const float*)d_in[4];
  const float* qv       = (const float*)d_in[5];
  const float* pos_bias = (const float*)d_in[6];
  const float* pw       = (const float*)d_in[7];
  const float* pg       = (const float*)d_in[8];
  const float* pbt      = (const float*)d_in[9];
  const float* pmn      = (const float*)d_in[10];
  const float* pvr      = (const float*)d_in[11];
  float* out = (float*)d_out;

  // ---- adaptive workspace: FIXED 16.85MB + G*43.55MB (outc/partials overlaid) ----
  const unsigned long FIXED = 16846848UL;
  const unsigned long PERG  = 43548672UL;
  long G = 1;
  if      (ws_size >= FIXED + PERG*16) G = 16;
  else if (ws_size >= FIXED + PERG*8)  G = 8;
  else if (ws_size >= FIXED + PERG*4)  G = 4;
  else if (ws_size >= FIXED + PERG*2)  G = 2;
  else if (ws_size >= FIXED + PERG)    G = 1;
  else return;

  char* ws = (char*)d_ws;
  unsigned short* wqb = (unsigned short*)(ws + 0L);            // 12,582,912
  unsigned short* wpb = (unsigned short*)(ws + 12582912L);     //  4,194,304
  float* sc_qkv       = (float*)(ws + 16777216L);              //     32,768
  float* sh_qkv       = (float*)(ws + 16809984L);              //     32,768
  float* sc_p         = (float*)(ws + 16842752L);              //      2,048
  float* sh_p         = (float*)(ws + 16844800L);              //      2,048
  const long gb = 16846848L;
  unsigned short* xbg   = (unsigned short*)(ws + gb);                      // G*1,572,864
  unsigned short* qkvg  = (unsigned short*)(ws + gb + G*1572864L);         // G*16,777,216
  unsigned short* Vtg   = (unsigned short*)(ws + gb + G*18350080L);        // G*8,388,608
  unsigned short* Eg    = (unsigned short*)(ws + gb + G*26738688L);        // G*16,777,216
  float* sumsg          = (float*)(ws + gb + G*43515904L);                 // G*32,768
  // overlays (dead-buffer reuse):
  unsigned short* outcg = qkvg;                 // qkv region dead after attn
  float* partials       = (float*)Eg;           // E region dead after PV

  // weights + BN affines (once)
  cast_bf16_kernel<<<dim3(3072), 256, 0, stream>>>(qkv_w, wqb, 786432);
  cast_bf16_kernel<<<dim3(1024), 256, 0, stream>>>(pw,    wpb, 262144);
  bn_precompute<<<dim3(32), 256, 0, stream>>>(qg, qb, qm, qv, sc_qkv, sh_qkv, 8192, 1);
  bn_precompute<<<dim3(2),  256, 0, stream>>>(pg, pbt, pmn, pvr, sc_p, sh_p, 512, 0);

  const int nG = (int)(16 / G);
  for (int g = 0; g < nG; g++){
    const float* xg = x + (long)g * G * 786432L;
    long mbase = (long)g * G * 1024L;

    cast_bf16_kernel<<<dim3((unsigned)(G*384)), 256, 0, stream>>>(xg, xbg, (int)(G*98304));

    // qkv = BN(x @ qkv_w^T) -> row-major [G*1024][8192]
    gemm_nt<0><<<dim3(64, (unsigned)(8*G), 1), 256, 0, stream>>>(
        xbg, wqb, 768, 0L, 0L, 0L, sc_qkv, sh_qkv, nullptr, qkvg, nullptr);

    // V slice -> Vt [bh][512][1024]
    transpose_v<<<dim3(16, 8, (unsigned)(8*G)), 256, 0, stream>>>(qkvg, Vtg);

    // E = exp(QK^T + bias), rowsums
    attn_scores<<<dim3(16, (unsigned)(8*G)), 128, 0, stream>>>(qkvg, pos_bias, Eg, sumsg);

    // outc = clamp((E @ V) / sum, -1, 1)  (overlays qkv region)
    gemm_nt<1><<<dim3(4, 8, (unsigned)(8*G)), 256, 0, stream>>>(
        Eg, Vtg, 1024, 1048576L, 524288L, 0L, nullptr, nullptr, sumsg, outcg, nullptr);

    // proj split-K=4 -> fp32 partials (overlays E region)
    gemm_nt<3><<<dim3(4, (unsigned)(8*G), 4), 256, 0, stream>>>(
        outcg, wpb, 4096, 0L, 0L, (long)(G*1024), nullptr, nullptr, nullptr,
        nullptr, partials);

    // out rows [mbase, ...) = (sum partials)*sc + sh
    reduce_bn<<<dim3((unsigned)(G*512)), 256, 0, stream>>>(
        partials, sc_p, sh_p, out, (long)(G*1024), mbase);
  }
}